// Round 8
// baseline (271.601 us; speedup 1.0000x reference)
//
#include <hip/hip_runtime.h>

// ---------------------------------------------------------------------------
// SpatialTransformer: conv1..3 (+relu+pool), BN+dense head -> theta,
// fused nearest-upsample+concat+bilinear-sampler+leaky-relu.
// All fp32. B=16, H=W=256, LOC_C=31.
// r8: conv2/conv3p split input-channel work across wave halves (32 px x 2
// ciq-halves per wave) -> 2x waves/CU and half the dependent-latency chain;
// shfl_down(32) pair reduction. d1b+theta fused (6 dispatches total).
// Padded layouts (Ap 130x130x8, Bp 66x66x16) keep all loads unguarded.
// ---------------------------------------------------------------------------

#define NEG_SLOPE 0.1f
#define BN_EPS 1e-3f

typedef float vfloat4 __attribute__((ext_vector_type(4)));

__device__ __forceinline__ void fma4v(float pv, float4 wq, float* __restrict__ acc) {
    acc[0] = fmaf(pv, wq.x, acc[0]);
    acc[1] = fmaf(pv, wq.y, acc[1]);
    acc[2] = fmaf(pv, wq.z, acc[2]);
    acc[3] = fmaf(pv, wq.w, acc[3]);
}

// K1: conv1 (1->8) + bias + relu + pool. x:(16,256,256,1) -> Ap (padded 130x130x8).
// Spare threads zero Ap/Bp borders.
__global__ __launch_bounds__(256) void st_conv1(const float* __restrict__ x,
                                                const float* __restrict__ w,
                                                const float* __restrict__ bias,
                                                float* __restrict__ Ap,
                                                float* __restrict__ Bp) {
    int idx = blockIdx.x * 256 + threadIdx.x;       // 262144
    int px = idx & 127, py = (idx >> 7) & 127, b = idx >> 14;
    const float* xb = x + b * 65536;
    int iy0 = 2 * py - 1, ix0 = 2 * px - 1;
    float p[16];
#pragma unroll
    for (int r = 0; r < 4; ++r) {
        int iy = iy0 + r;
        bool oky = (iy >= 0) && (iy < 256);
#pragma unroll
        for (int cc = 0; cc < 4; ++cc) {
            int ix = ix0 + cc;
            bool ok = oky && (ix >= 0) && (ix < 256);
            p[r * 4 + cc] = ok ? xb[iy * 256 + ix] : 0.0f;
        }
    }
    float m[8];
#pragma unroll
    for (int co = 0; co < 8; ++co) m[co] = -1e30f;
#pragma unroll
    for (int oy = 0; oy < 2; ++oy)
#pragma unroll
        for (int ox = 0; ox < 2; ++ox) {
            float acc[8];
#pragma unroll
            for (int co = 0; co < 8; ++co) acc[co] = 0.0f;
#pragma unroll
            for (int ky = 0; ky < 3; ++ky)
#pragma unroll
                for (int kx = 0; kx < 3; ++kx) {
                    float pv = p[(oy + ky) * 4 + (ox + kx)];
                    const float* wr = w + (ky * 3 + kx) * 8;
#pragma unroll
                    for (int co = 0; co < 8; ++co)
                        acc[co] = fmaf(pv, wr[co], acc[co]);
                }
#pragma unroll
            for (int co = 0; co < 8; ++co) m[co] = fmaxf(m[co], acc[co]);
        }
    float4 o0, o1;
    float r0 = m[0] + bias[0], r1 = m[1] + bias[1], r2 = m[2] + bias[2], r3 = m[3] + bias[3];
    float r4 = m[4] + bias[4], r5 = m[5] + bias[5], r6 = m[6] + bias[6], r7 = m[7] + bias[7];
    o0.x = r0 > 0.f ? r0 : 0.f; o0.y = r1 > 0.f ? r1 : 0.f;
    o0.z = r2 > 0.f ? r2 : 0.f; o0.w = r3 > 0.f ? r3 : 0.f;
    o1.x = r4 > 0.f ? r4 : 0.f; o1.y = r5 > 0.f ? r5 : 0.f;
    o1.z = r6 > 0.f ? r6 : 0.f; o1.w = r7 > 0.f ? r7 : 0.f;
    float* o = Ap + ((b * 130 + py + 1) * 130 + (px + 1)) * 8;
    *(float4*)o = o0;
    *(float4*)(o + 4) = o1;

    const float4 z4 = {0.f, 0.f, 0.f, 0.f};
    if (idx < 8256) {                               // Ap border
        int bb = idx / 516, t = idx - bb * 516;
        int iy, ix;
        if (t < 130)      { iy = 0;       ix = t; }
        else if (t < 260) { iy = 129;     ix = t - 130; }
        else if (t < 388) { iy = t - 259; ix = 0; }
        else              { iy = t - 387; ix = 129; }
        float* d = Ap + ((bb * 130 + iy) * 130 + ix) * 8;
        *(float4*)d = z4; *(float4*)(d + 4) = z4;
    } else if (idx < 12416) {                       // Bp border
        int r = idx - 8256;
        int bb = r / 260, t = r - bb * 260;
        int iy, ix;
        if (t < 66)       { iy = 0;       ix = t; }
        else if (t < 132) { iy = 65;      ix = t - 66; }
        else if (t < 196) { iy = t - 131; ix = 0; }
        else              { iy = t - 195; ix = 65; }
        float* d = Bp + ((bb * 66 + iy) * 66 + ix) * 16;
        *(float4*)d = z4; *(float4*)(d + 4) = z4;
        *(float4*)(d + 8) = z4; *(float4*)(d + 12) = z4;
    }
}

// K2: conv2 (8->16) + bias + relu + pool. Ap(padded) -> Bp(padded interior).
// Wave = 32 px x 2 ciq-halves; wave index = co-quad. 2048 blocks (32 waves/CU).
__global__ __launch_bounds__(256) void st_conv2(const float* __restrict__ Ap,
                                                const float* __restrict__ w,
                                                const float* __restrict__ bias,
                                                float* __restrict__ Bp) {
    __shared__ __align__(16) float wlds[1152];
    int t = threadIdx.x;
    for (int i = t; i < 1152; i += 256) wlds[i] = w[i];
    __syncthreads();
    int lane = t & 63;
    int ciq = lane >> 5;                               // 0/1 per wave-half
    int wv = __builtin_amdgcn_readfirstlane(t >> 6);   // co-quad 0..3
    int cobase = wv * 4;
    int pixel = blockIdx.x * 32 + (lane & 31);         // 65536 pooled px
    int px = pixel & 63, py = (pixel >> 6) & 63, b = pixel >> 12;
    const float* Ab = Ap + b * 135200;                 // 130*130*8
    int rowbase = (2 * py) * 130 + 2 * px;
    float acc[4][4];
#pragma unroll
    for (int pos = 0; pos < 4; ++pos)
#pragma unroll
        for (int c = 0; c < 4; ++c) acc[pos][c] = 0.0f;

    float ps[64];                                      // [cell16][comp4]
#pragma unroll
    for (int r = 0; r < 4; ++r)
#pragma unroll
        for (int cc = 0; cc < 4; ++cc) {
            float4 v = *(const float4*)(Ab + (rowbase + r * 130 + cc) * 8 + ciq * 4);
            int cell = r * 4 + cc;
            ps[cell * 4 + 0] = v.x; ps[cell * 4 + 1] = v.y;
            ps[cell * 4 + 2] = v.z; ps[cell * 4 + 3] = v.w;
        }
#pragma unroll
    for (int ky = 0; ky < 3; ++ky)
#pragma unroll
        for (int kx = 0; kx < 3; ++kx) {
            int tap = ky * 3 + kx;
#pragma unroll
            for (int comp = 0; comp < 4; ++comp) {
                float4 wq = *(const float4*)&wlds[((tap * 8 + ciq * 4 + comp) << 4) + cobase];
#pragma unroll
                for (int oy = 0; oy < 2; ++oy)
#pragma unroll
                    for (int ox = 0; ox < 2; ++ox) {
                        float pv = ps[((oy + ky) * 4 + (ox + kx)) * 4 + comp];
                        fma4v(pv, wq, acc[oy * 2 + ox]);
                    }
            }
        }
    // pair-reduce ciq halves (lane, lane+32)
#pragma unroll
    for (int pos = 0; pos < 4; ++pos)
#pragma unroll
        for (int c = 0; c < 4; ++c)
            acc[pos][c] += __shfl_down(acc[pos][c], 32, 64);
    if (ciq == 0) {
        float4 o;
        float* oc = (float*)&o;
#pragma unroll
        for (int c = 0; c < 4; ++c) {
            float m = fmaxf(fmaxf(acc[0][c], acc[1][c]), fmaxf(acc[2][c], acc[3][c]));
            m += bias[cobase + c];
            oc[c] = m > 0.0f ? m : 0.0f;
        }
        *(float4*)(Bp + ((b * 66 + py + 1) * 66 + (px + 1)) * 16 + cobase) = o;
    }
}

// K3: FUSED conv3 (16->31) + bias + relu + pool + BN. Bp -> xip + fprime[j][16b].
// Wave = 32 px x 2 ciq-halves (2 ciq each); quad = blockIdx.y*4 + wave.
// Grid (512,2) -> 16 waves/CU.
__global__ __launch_bounds__(256) void st_conv3p(const float* __restrict__ Bp,
                                                 const float* __restrict__ w,
                                                 const float* __restrict__ bias,
                                                 const float* __restrict__ gamma,
                                                 const float* __restrict__ beta,
                                                 const float* __restrict__ mean,
                                                 const float* __restrict__ var,
                                                 float* __restrict__ xip,
                                                 float* __restrict__ fprime) {
    __shared__ __align__(16) float wlds[9 * 16 * 32];  // stride-32 padded
    int t = threadIdx.x;
    for (int i = t; i < 4464; i += 256) {
        int tapci = i / 31;
        int co = i - tapci * 31;
        wlds[(tapci << 5) + co] = w[i];
    }
    __syncthreads();
    int lane = t & 63;
    int half = lane >> 5;                              // ciq pair {2h, 2h+1}
    int wv = __builtin_amdgcn_readfirstlane(t >> 6);   // 0..3
    int quad = blockIdx.y * 4 + wv;                    // 0..7
    int cobase = quad * 4;
    if (cobase > 27) cobase = 27;
    int pixel = blockIdx.x * 32 + (lane & 31);         // 16384 pooled px
    int b = pixel >> 10;
    int cell = pixel & 1023;
    int ppy = cell >> 5, ppx = cell & 31;
    const float* Bb = Bp + b * 69696;                  // 66*66*16
    int rowbase = (2 * ppy) * 66 + 2 * ppx;
    float acc[4][4];
#pragma unroll
    for (int pos = 0; pos < 4; ++pos)
#pragma unroll
        for (int c = 0; c < 4; ++c) acc[pos][c] = 0.0f;

#pragma unroll
    for (int ii = 0; ii < 2; ++ii) {
        int ciq = half * 2 + ii;
        float ps[64];
#pragma unroll
        for (int r = 0; r < 4; ++r)
#pragma unroll
            for (int cc = 0; cc < 4; ++cc) {
                float4 v = *(const float4*)(Bb + (rowbase + r * 66 + cc) * 16 + ciq * 4);
                int cell2 = r * 4 + cc;
                ps[cell2 * 4 + 0] = v.x; ps[cell2 * 4 + 1] = v.y;
                ps[cell2 * 4 + 2] = v.z; ps[cell2 * 4 + 3] = v.w;
            }
#pragma unroll
        for (int ky = 0; ky < 3; ++ky)
#pragma unroll
            for (int kx = 0; kx < 3; ++kx) {
                int tap = ky * 3 + kx;
#pragma unroll
                for (int comp = 0; comp < 4; ++comp) {
                    float4 wq = *(const float4*)&wlds[((tap * 16 + ciq * 4 + comp) << 5) + cobase];
#pragma unroll
                    for (int oy = 0; oy < 2; ++oy)
#pragma unroll
                        for (int ox = 0; ox < 2; ++ox) {
                            float pv = ps[((oy + ky) * 4 + (ox + kx)) * 4 + comp];
                            fma4v(pv, wq, acc[oy * 2 + ox]);
                        }
                }
            }
    }
    // pair-reduce ciq halves
#pragma unroll
    for (int pos = 0; pos < 4; ++pos)
#pragma unroll
        for (int c = 0; c < 4; ++c)
            acc[pos][c] += __shfl_down(acc[pos][c], 32, 64);
    if (half == 0) {
        float* xcell = xip + (b << 15) + (cell << 5) + 1 + cobase;  // slot = 1+co
#pragma unroll
        for (int c = 0; c < 4; ++c) {
            float m = fmaxf(fmaxf(acc[0][c], acc[1][c]), fmaxf(acc[2][c], acc[3][c]));
            m += bias[cobase + c];
            float v = m > 0.0f ? m : 0.0f;
            xcell[c] = v;
            int j = cell * 31 + cobase + c;
            float sc = gamma[j] * rsqrtf(var[j] + BN_EPS);
            fprime[j * 16 + b] = (v - mean[j]) * sc + beta[j];
        }
    }
}

// K4: split-K GEMM d1. fp layout [j][16b] -> s_load_dwordx16 per j; lane=o ->
// coalesced k1 reads. 496 blocks x 4 waves x 16 j.
__global__ __launch_bounds__(256) void st_d1(const float* __restrict__ fp,
                                             const float* __restrict__ k1,
                                             float* __restrict__ partial) {
    int t = threadIdx.x, s = blockIdx.x;           // 496 blocks
    int o = t & 63;
    int sub = t >> 6;
    int subu = __builtin_amdgcn_readfirstlane(sub);
    int j0 = s * 64 + subu * 16;
    float acc[16];
#pragma unroll
    for (int b = 0; b < 16; ++b) acc[b] = 0.0f;
#pragma unroll 4
    for (int jj = 0; jj < 16; ++jj) {
        int j = j0 + jj;
        float kv = k1[j * 64 + o];
        const float* fpj = fp + j * 16;
#pragma unroll
        for (int b = 0; b < 16; ++b)
            acc[b] = fmaf(fpj[b], kv, acc[b]);
    }
    __shared__ float red[4][16][64];
#pragma unroll
    for (int b = 0; b < 16; ++b) red[sub][b][o] = acc[b];
    __syncthreads();
    if (sub == 0) {
#pragma unroll
        for (int b = 0; b < 16; ++b) {
            float v = red[0][b][o] + red[1][b][o] + red[2][b][o] + red[3][b][o];
            partial[(s * 64 + o) * 16 + b] = v;
        }
    }
}

// K5: FUSED d1-reduce + bias/relu + d2 (relu) + d3 -> theta. One block/batch.
__global__ __launch_bounds__(128) void st_head(const float* __restrict__ partial,
                                               const float* __restrict__ b1,
                                               const float* __restrict__ k2,
                                               const float* __restrict__ b2,
                                               const float* __restrict__ k3,
                                               const float* __restrict__ b3,
                                               float* __restrict__ theta) {
    int b = blockIdx.x, t = threadIdx.x;
    __shared__ float h1[64];
    __shared__ float h2[96];
    if (t < 64) {
        float s = 0.0f;
#pragma unroll 8
        for (int sl = 0; sl < 496; ++sl) s += partial[(sl * 64 + t) * 16 + b];
        s += b1[t];
        h1[t] = s > 0.0f ? s : 0.0f;
    }
    __syncthreads();
    if (t < 96) {
        float s = b2[t];
        for (int i = 0; i < 64; ++i) s = fmaf(h1[i], k2[i * 96 + t], s);
        h2[t] = s > 0.0f ? s : 0.0f;
    }
    __syncthreads();
    if (t < 6) {
        float s = b3[t];
        for (int i = 0; i < 96; ++i) s = fmaf(h2[i], k3[i * 6 + t], s);
        theta[b * 6 + t] = s;
    }
}

// K6: fused grid-gen + upsample-concat + bilinear sampler + leaky relu.
// 4 threads per pixel (quad q -> out channels [8q,8q+8)). No LDS; coalesced
// 32B/lane nontemporal stores; 2 aligned float4 gathers per tap.
__global__ __launch_bounds__(256) void st_sample(const float* __restrict__ x,
                                                 const float* __restrict__ xip,
                                                 const float* __restrict__ theta,
                                                 float* __restrict__ out) {
    int gid = blockIdx.x * 256 + threadIdx.x;      // 4,194,304
    int q = gid & 3;
    int pix = gid >> 2;                            // 1,048,576 pixels
    int ow = pix & 255, oh = (pix >> 8) & 255;
    int b = __builtin_amdgcn_readfirstlane(blockIdx.x >> 10);

    const float* th = theta + b * 6;
    float t0 = th[0], t1 = th[1], t2 = th[2], t3 = th[3], t4 = th[4], t5 = th[5];
    float gx = (float)ow * (2.0f / 255.0f) - 1.0f;
    float gy = (float)oh * (2.0f / 255.0f) - 1.0f;
    float sx = gx * t0 + gy * t3 + t2;
    float sy = gx * t1 + gy * t4 + t5;
    float xf = 0.5f * ((sx + 1.0f) * 255.0f);
    float yf = 0.5f * ((sy + 1.0f) * 255.0f);
    float x0 = floorf(xf), y0 = floorf(yf);
    float x1 = x0 + 1.0f, y1 = y0 + 1.0f;
    x0 = fminf(fmaxf(x0, 0.0f), 255.0f);
    x1 = fminf(fmaxf(x1, 0.0f), 255.0f);
    y0 = fminf(fmaxf(y0, 0.0f), 255.0f);
    y1 = fminf(fmaxf(y1, 0.0f), 255.0f);
    float wa = (x1 - xf) * (y1 - yf);
    float wb = (x1 - xf) * (yf - y0);
    float wc = (xf - x0) * (y1 - yf);
    float wd = (xf - x0) * (yf - y0);
    int xi0 = (int)x0, xi1 = (int)x1, yi0 = (int)y0, yi1 = (int)y1;

    const float* cellbase = xip + (b << 15);
    int off = q * 8;
    const float* pa = cellbase + ((((yi0 >> 3) << 5) + (xi0 >> 3)) << 5) + off;
    const float* pb = cellbase + ((((yi1 >> 3) << 5) + (xi0 >> 3)) << 5) + off;
    const float* pc = cellbase + ((((yi0 >> 3) << 5) + (xi1 >> 3)) << 5) + off;
    const float* pd = cellbase + ((((yi1 >> 3) << 5) + (xi1 >> 3)) << 5) + off;

    float r[8];
#pragma unroll
    for (int k = 0; k < 2; ++k) {
        float4 va = *(const float4*)(pa + 4 * k);
        float4 vb = *(const float4*)(pb + 4 * k);
        float4 vc = *(const float4*)(pc + 4 * k);
        float4 vd = *(const float4*)(pd + 4 * k);
        r[4 * k]     = fmaf(wa, va.x, fmaf(wb, vb.x, fmaf(wc, vc.x, wd * vd.x)));
        r[4 * k + 1] = fmaf(wa, va.y, fmaf(wb, vb.y, fmaf(wc, vc.y, wd * vd.y)));
        r[4 * k + 2] = fmaf(wa, va.z, fmaf(wb, vb.z, fmaf(wc, vc.z, wd * vd.z)));
        r[4 * k + 3] = fmaf(wa, va.w, fmaf(wb, vb.w, fmaf(wc, vc.w, wd * vd.w)));
    }
    if (q == 0) {
        const float* xb = x + b * 65536;
        float Ia = xb[yi0 * 256 + xi0];
        float Ib = xb[yi1 * 256 + xi0];
        float Ic = xb[yi0 * 256 + xi1];
        float Id = xb[yi1 * 256 + xi1];
        r[0] = fmaf(wa, Ia, fmaf(wb, Ib, fmaf(wc, Ic, wd * Id)));
    }
#pragma unroll
    for (int i = 0; i < 8; ++i) r[i] = r[i] >= 0.0f ? r[i] : NEG_SLOPE * r[i];

    float* ob = out + pix * 32 + off;
    vfloat4 v0 = {r[0], r[1], r[2], r[3]};
    vfloat4 v1 = {r[4], r[5], r[6], r[7]};
    __builtin_nontemporal_store(v0, (vfloat4*)ob);
    __builtin_nontemporal_store(v1, (vfloat4*)(ob + 4));
}

extern "C" void kernel_launch(void* const* d_in, const int* in_sizes, int n_in,
                              void* d_out, int out_size, void* d_ws, size_t ws_size,
                              hipStream_t stream) {
    const float* x     = (const float*)d_in[0];
    const float* c1k   = (const float*)d_in[1];
    const float* c1b   = (const float*)d_in[2];
    const float* c2k   = (const float*)d_in[3];
    const float* c2b   = (const float*)d_in[4];
    const float* c3k   = (const float*)d_in[5];
    const float* c3b   = (const float*)d_in[6];
    const float* gamma = (const float*)d_in[7];
    const float* beta  = (const float*)d_in[8];
    const float* mean  = (const float*)d_in[9];
    const float* var   = (const float*)d_in[10];
    const float* d1k   = (const float*)d_in[11];
    const float* d1b   = (const float*)d_in[12];
    const float* d2k   = (const float*)d_in[13];
    const float* d2b   = (const float*)d_in[14];
    const float* d3k   = (const float*)d_in[15];
    const float* d3b   = (const float*)d_in[16];
    float* out = (float*)d_out;
    float* ws  = (float*)d_ws;

    float* Ap      = ws;                           // 16*130*130*8 = 2163200
    float* Bp      = ws + 2163200;                 // 16*66*66*16 = 1115136
    float* xip     = ws;                           // 524288 (reuse Ap)
    float* fprime  = ws + 524288;                  // 507904 (reuse Ap)
    float* partial = ws + 3278336;                 // 496*64*16 = 507904
    float* theta   = ws + 3786240;                 // 96

    st_conv1<<<1024, 256, 0, stream>>>(x, c1k, c1b, Ap, Bp);
    st_conv2<<<2048, 256, 0, stream>>>(Ap, c2k, c2b, Bp);
    st_conv3p<<<dim3(512, 2), 256, 0, stream>>>(Bp, c3k, c3b, gamma, beta,
                                                mean, var, xip, fprime);
    st_d1<<<496, 256, 0, stream>>>(fprime, d1k, partial);
    st_head<<<16, 128, 0, stream>>>(partial, d1b, d2k, d2b, d3k, d3b, theta);
    st_sample<<<16384, 256, 0, stream>>>(x, xip, theta, out);
}

// Round 9
// 251.534 us; speedup vs baseline: 1.0798x; 1.0798x over previous
//
#include <hip/hip_runtime.h>

// ---------------------------------------------------------------------------
// SpatialTransformer: conv1..3 (+relu+pool), BN+dense head -> theta,
// fused nearest-upsample+concat+bilinear-sampler+leaky-relu.
// All fp32. B=16, H=W=256, LOC_C=31.
// r9 = best-of: r7 convs (LDS weights, wave-uniform co-quad, padded
// unguarded loads) + fused 256-thread head (4-way split reduce) + 4-thread/px
// sampler with nontemporal coalesced stores. 6 dispatches.
// ---------------------------------------------------------------------------

#define NEG_SLOPE 0.1f
#define BN_EPS 1e-3f

typedef float vfloat4 __attribute__((ext_vector_type(4)));

__device__ __forceinline__ void fma4v(float pv, float4 wq, float* __restrict__ acc) {
    acc[0] = fmaf(pv, wq.x, acc[0]);
    acc[1] = fmaf(pv, wq.y, acc[1]);
    acc[2] = fmaf(pv, wq.z, acc[2]);
    acc[3] = fmaf(pv, wq.w, acc[3]);
}

// K1: conv1 (1->8) + bias + relu + pool. x:(16,256,256,1) -> Ap (padded 130x130x8).
// Spare threads zero Ap/Bp borders.
__global__ __launch_bounds__(256) void st_conv1(const float* __restrict__ x,
                                                const float* __restrict__ w,
                                                const float* __restrict__ bias,
                                                float* __restrict__ Ap,
                                                float* __restrict__ Bp) {
    int idx = blockIdx.x * 256 + threadIdx.x;       // 262144
    int px = idx & 127, py = (idx >> 7) & 127, b = idx >> 14;
    const float* xb = x + b * 65536;
    int iy0 = 2 * py - 1, ix0 = 2 * px - 1;
    float p[16];
#pragma unroll
    for (int r = 0; r < 4; ++r) {
        int iy = iy0 + r;
        bool oky = (iy >= 0) && (iy < 256);
#pragma unroll
        for (int cc = 0; cc < 4; ++cc) {
            int ix = ix0 + cc;
            bool ok = oky && (ix >= 0) && (ix < 256);
            p[r * 4 + cc] = ok ? xb[iy * 256 + ix] : 0.0f;
        }
    }
    float m[8];
#pragma unroll
    for (int co = 0; co < 8; ++co) m[co] = -1e30f;
#pragma unroll
    for (int oy = 0; oy < 2; ++oy)
#pragma unroll
        for (int ox = 0; ox < 2; ++ox) {
            float acc[8];
#pragma unroll
            for (int co = 0; co < 8; ++co) acc[co] = 0.0f;
#pragma unroll
            for (int ky = 0; ky < 3; ++ky)
#pragma unroll
                for (int kx = 0; kx < 3; ++kx) {
                    float pv = p[(oy + ky) * 4 + (ox + kx)];
                    const float* wr = w + (ky * 3 + kx) * 8;
#pragma unroll
                    for (int co = 0; co < 8; ++co)
                        acc[co] = fmaf(pv, wr[co], acc[co]);
                }
#pragma unroll
            for (int co = 0; co < 8; ++co) m[co] = fmaxf(m[co], acc[co]);
        }
    float4 o0, o1;
    float r0 = m[0] + bias[0], r1 = m[1] + bias[1], r2 = m[2] + bias[2], r3 = m[3] + bias[3];
    float r4 = m[4] + bias[4], r5 = m[5] + bias[5], r6 = m[6] + bias[6], r7 = m[7] + bias[7];
    o0.x = r0 > 0.f ? r0 : 0.f; o0.y = r1 > 0.f ? r1 : 0.f;
    o0.z = r2 > 0.f ? r2 : 0.f; o0.w = r3 > 0.f ? r3 : 0.f;
    o1.x = r4 > 0.f ? r4 : 0.f; o1.y = r5 > 0.f ? r5 : 0.f;
    o1.z = r6 > 0.f ? r6 : 0.f; o1.w = r7 > 0.f ? r7 : 0.f;
    float* o = Ap + ((b * 130 + py + 1) * 130 + (px + 1)) * 8;
    *(float4*)o = o0;
    *(float4*)(o + 4) = o1;

    const float4 z4 = {0.f, 0.f, 0.f, 0.f};
    if (idx < 8256) {                               // Ap border
        int bb = idx / 516, t = idx - bb * 516;
        int iy, ix;
        if (t < 130)      { iy = 0;       ix = t; }
        else if (t < 260) { iy = 129;     ix = t - 130; }
        else if (t < 388) { iy = t - 259; ix = 0; }
        else              { iy = t - 387; ix = 129; }
        float* d = Ap + ((bb * 130 + iy) * 130 + ix) * 8;
        *(float4*)d = z4; *(float4*)(d + 4) = z4;
    } else if (idx < 12416) {                       // Bp border
        int r = idx - 8256;
        int bb = r / 260, t = r - bb * 260;
        int iy, ix;
        if (t < 66)       { iy = 0;       ix = t; }
        else if (t < 132) { iy = 65;      ix = t - 66; }
        else if (t < 196) { iy = t - 131; ix = 0; }
        else              { iy = t - 195; ix = 65; }
        float* d = Bp + ((bb * 66 + iy) * 66 + ix) * 16;
        *(float4*)d = z4; *(float4*)(d + 4) = z4;
        *(float4*)(d + 8) = z4; *(float4*)(d + 12) = z4;
    }
}

// K2: conv2 (8->16) + bias + relu + pool. Ap(padded) -> Bp(padded interior).
// thread = (pooled px, co-quad); LDS weights; UNGUARDED float4 loads. (r7)
__global__ __launch_bounds__(256) void st_conv2(const float* __restrict__ Ap,
                                                const float* __restrict__ w,
                                                const float* __restrict__ bias,
                                                float* __restrict__ Bp) {
    __shared__ __align__(16) float wlds[1152];
    int t = threadIdx.x;
    for (int i = t; i < 1152; i += 256) wlds[i] = w[i];
    __syncthreads();
    int lane = t & 63;
    int wv = __builtin_amdgcn_readfirstlane(t >> 6);   // 0..3 co-quad
    int cobase = wv * 4;
    int pixel = blockIdx.x * 64 + lane;                // 65536 pooled px
    int px = pixel & 63, py = (pixel >> 6) & 63, b = pixel >> 12;
    const float* Ab = Ap + b * 135200;                 // 130*130*8
    int rowbase = (2 * py) * 130 + 2 * px;
    float acc[4][4];
#pragma unroll
    for (int pos = 0; pos < 4; ++pos)
#pragma unroll
        for (int c = 0; c < 4; ++c) acc[pos][c] = 0.0f;

#pragma unroll
    for (int ciq = 0; ciq < 2; ++ciq) {
        float ps[64];                                  // [cell16][comp4]
#pragma unroll
        for (int r = 0; r < 4; ++r)
#pragma unroll
            for (int cc = 0; cc < 4; ++cc) {
                float4 v = *(const float4*)(Ab + (rowbase + r * 130 + cc) * 8 + ciq * 4);
                int cell = r * 4 + cc;
                ps[cell * 4 + 0] = v.x; ps[cell * 4 + 1] = v.y;
                ps[cell * 4 + 2] = v.z; ps[cell * 4 + 3] = v.w;
            }
#pragma unroll
        for (int ky = 0; ky < 3; ++ky)
#pragma unroll
            for (int kx = 0; kx < 3; ++kx) {
                int tap = ky * 3 + kx;
#pragma unroll
                for (int comp = 0; comp < 4; ++comp) {
                    float4 wq = *(const float4*)&wlds[((tap * 8 + ciq * 4 + comp) << 4) + cobase];
#pragma unroll
                    for (int oy = 0; oy < 2; ++oy)
#pragma unroll
                        for (int ox = 0; ox < 2; ++ox) {
                            float pv = ps[((oy + ky) * 4 + (ox + kx)) * 4 + comp];
                            fma4v(pv, wq, acc[oy * 2 + ox]);
                        }
                }
            }
    }
    float4 o;
    float* oc = (float*)&o;
#pragma unroll
    for (int c = 0; c < 4; ++c) {
        float m = fmaxf(fmaxf(acc[0][c], acc[1][c]), fmaxf(acc[2][c], acc[3][c]));
        m += bias[cobase + c];
        oc[c] = m > 0.0f ? m : 0.0f;
    }
    *(float4*)(Bp + ((b * 66 + py + 1) * 66 + (px + 1)) * 16 + cobase) = o;
}

// K3: FUSED conv3 (16->31) + bias + relu + pool + BN. Bp -> xip + fprime[j][16b].
// thread = (pooled px, co-quad); grid (256,2); UNGUARDED loads; LDS weights. (r7)
__global__ __launch_bounds__(256) void st_conv3p(const float* __restrict__ Bp,
                                                 const float* __restrict__ w,
                                                 const float* __restrict__ bias,
                                                 const float* __restrict__ gamma,
                                                 const float* __restrict__ beta,
                                                 const float* __restrict__ mean,
                                                 const float* __restrict__ var,
                                                 float* __restrict__ xip,
                                                 float* __restrict__ fprime) {
    __shared__ __align__(16) float wlds[9 * 16 * 32];  // stride-32 padded
    int t = threadIdx.x;
    for (int i = t; i < 4464; i += 256) {
        int tapci = i / 31;
        int co = i - tapci * 31;
        wlds[(tapci << 5) + co] = w[i];
    }
    __syncthreads();
    int lane = t & 63;
    int wv = __builtin_amdgcn_readfirstlane(t >> 6);   // 0..3
    int quad = blockIdx.y * 4 + wv;                    // 0..7
    int cobase = quad * 4;
    if (cobase > 27) cobase = 27;
    int pixel = blockIdx.x * 64 + lane;                // 16384 pooled px
    int b = pixel >> 10;
    int cell = pixel & 1023;
    int ppy = cell >> 5, ppx = cell & 31;
    const float* Bb = Bp + b * 69696;                  // 66*66*16
    int rowbase = (2 * ppy) * 66 + 2 * ppx;
    float acc[4][4];
#pragma unroll
    for (int pos = 0; pos < 4; ++pos)
#pragma unroll
        for (int c = 0; c < 4; ++c) acc[pos][c] = 0.0f;

#pragma unroll 2
    for (int ciq = 0; ciq < 4; ++ciq) {
        float ps[64];
#pragma unroll
        for (int r = 0; r < 4; ++r)
#pragma unroll
            for (int cc = 0; cc < 4; ++cc) {
                float4 v = *(const float4*)(Bb + (rowbase + r * 66 + cc) * 16 + ciq * 4);
                int cell2 = r * 4 + cc;
                ps[cell2 * 4 + 0] = v.x; ps[cell2 * 4 + 1] = v.y;
                ps[cell2 * 4 + 2] = v.z; ps[cell2 * 4 + 3] = v.w;
            }
#pragma unroll
        for (int ky = 0; ky < 3; ++ky)
#pragma unroll
            for (int kx = 0; kx < 3; ++kx) {
                int tap = ky * 3 + kx;
#pragma unroll
                for (int comp = 0; comp < 4; ++comp) {
                    float4 wq = *(const float4*)&wlds[((tap * 16 + ciq * 4 + comp) << 5) + cobase];
#pragma unroll
                    for (int oy = 0; oy < 2; ++oy)
#pragma unroll
                        for (int ox = 0; ox < 2; ++ox) {
                            float pv = ps[((oy + ky) * 4 + (ox + kx)) * 4 + comp];
                            fma4v(pv, wq, acc[oy * 2 + ox]);
                        }
                }
            }
    }
    float* xcell = xip + (b << 15) + (cell << 5) + 1 + cobase;  // slot = 1+co
#pragma unroll
    for (int c = 0; c < 4; ++c) {
        float m = fmaxf(fmaxf(acc[0][c], acc[1][c]), fmaxf(acc[2][c], acc[3][c]));
        m += bias[cobase + c];
        float v = m > 0.0f ? m : 0.0f;
        xcell[c] = v;
        int j = cell * 31 + cobase + c;
        float sc = gamma[j] * rsqrtf(var[j] + BN_EPS);
        fprime[j * 16 + b] = (v - mean[j]) * sc + beta[j];
    }
}

// K4: split-K GEMM d1. fp layout [j][16b] -> s_load_dwordx16 per j; lane=o ->
// coalesced k1 reads. 496 blocks x 4 waves x 16 j.
__global__ __launch_bounds__(256) void st_d1(const float* __restrict__ fp,
                                             const float* __restrict__ k1,
                                             float* __restrict__ partial) {
    int t = threadIdx.x, s = blockIdx.x;           // 496 blocks
    int o = t & 63;
    int sub = t >> 6;
    int subu = __builtin_amdgcn_readfirstlane(sub);
    int j0 = s * 64 + subu * 16;
    float acc[16];
#pragma unroll
    for (int b = 0; b < 16; ++b) acc[b] = 0.0f;
#pragma unroll 4
    for (int jj = 0; jj < 16; ++jj) {
        int j = j0 + jj;
        float kv = k1[j * 64 + o];
        const float* fpj = fp + j * 16;
#pragma unroll
        for (int b = 0; b < 16; ++b)
            acc[b] = fmaf(fpj[b], kv, acc[b]);
    }
    __shared__ float red[4][16][64];
#pragma unroll
    for (int b = 0; b < 16; ++b) red[sub][b][o] = acc[b];
    __syncthreads();
    if (sub == 0) {
#pragma unroll
        for (int b = 0; b < 16; ++b) {
            float v = red[0][b][o] + red[1][b][o] + red[2][b][o] + red[3][b][o];
            partial[(s * 64 + o) * 16 + b] = v;
        }
    }
}

// K5: FUSED d1-reduce (4-way split over 256 threads) + bias/relu + d2 (relu)
// + d3 -> theta. One block per batch.
__global__ __launch_bounds__(256) void st_head(const float* __restrict__ partial,
                                               const float* __restrict__ b1,
                                               const float* __restrict__ k2,
                                               const float* __restrict__ b2,
                                               const float* __restrict__ k3,
                                               const float* __restrict__ b3,
                                               float* __restrict__ theta) {
    int b = blockIdx.x, t = threadIdx.x;
    __shared__ float red[4][64];
    __shared__ float h1[64];
    __shared__ float h2[96];
    int o = t & 63, qq = t >> 6;
    float s = 0.0f;
    int sl0 = qq * 124;
#pragma unroll 4
    for (int sl = sl0; sl < sl0 + 124; ++sl)
        s += partial[(sl * 64 + o) * 16 + b];
    red[qq][o] = s;
    __syncthreads();
    if (t < 64) {
        float v = red[0][t] + red[1][t] + red[2][t] + red[3][t] + b1[t];
        h1[t] = v > 0.0f ? v : 0.0f;
    }
    __syncthreads();
    if (t < 96) {
        float v = b2[t];
        for (int i = 0; i < 64; ++i) v = fmaf(h1[i], k2[i * 96 + t], v);
        h2[t] = v > 0.0f ? v : 0.0f;
    }
    __syncthreads();
    if (t < 6) {
        float v = b3[t];
        for (int i = 0; i < 96; ++i) v = fmaf(h2[i], k3[i * 6 + t], v);
        theta[b * 6 + t] = v;
    }
}

// K6: fused grid-gen + upsample-concat + bilinear sampler + leaky relu.
// 4 threads per pixel (quad q -> out channels [8q,8q+8)). No LDS; coalesced
// 32B/lane nontemporal stores; 2 aligned float4 gathers per tap.
__global__ __launch_bounds__(256) void st_sample(const float* __restrict__ x,
                                                 const float* __restrict__ xip,
                                                 const float* __restrict__ theta,
                                                 float* __restrict__ out) {
    int gid = blockIdx.x * 256 + threadIdx.x;      // 4,194,304
    int q = gid & 3;
    int pix = gid >> 2;                            // 1,048,576 pixels
    int ow = pix & 255, oh = (pix >> 8) & 255;
    int b = __builtin_amdgcn_readfirstlane(blockIdx.x >> 10);

    const float* th = theta + b * 6;
    float t0 = th[0], t1 = th[1], t2 = th[2], t3 = th[3], t4 = th[4], t5 = th[5];
    float gx = (float)ow * (2.0f / 255.0f) - 1.0f;
    float gy = (float)oh * (2.0f / 255.0f) - 1.0f;
    float sx = gx * t0 + gy * t3 + t2;
    float sy = gx * t1 + gy * t4 + t5;
    float xf = 0.5f * ((sx + 1.0f) * 255.0f);
    float yf = 0.5f * ((sy + 1.0f) * 255.0f);
    float x0 = floorf(xf), y0 = floorf(yf);
    float x1 = x0 + 1.0f, y1 = y0 + 1.0f;
    x0 = fminf(fmaxf(x0, 0.0f), 255.0f);
    x1 = fminf(fmaxf(x1, 0.0f), 255.0f);
    y0 = fminf(fmaxf(y0, 0.0f), 255.0f);
    y1 = fminf(fmaxf(y1, 0.0f), 255.0f);
    float wa = (x1 - xf) * (y1 - yf);
    float wb = (x1 - xf) * (yf - y0);
    float wc = (xf - x0) * (y1 - yf);
    float wd = (xf - x0) * (yf - y0);
    int xi0 = (int)x0, xi1 = (int)x1, yi0 = (int)y0, yi1 = (int)y1;

    const float* cellbase = xip + (b << 15);
    int off = q * 8;
    const float* pa = cellbase + ((((yi0 >> 3) << 5) + (xi0 >> 3)) << 5) + off;
    const float* pb = cellbase + ((((yi1 >> 3) << 5) + (xi0 >> 3)) << 5) + off;
    const float* pc = cellbase + ((((yi0 >> 3) << 5) + (xi1 >> 3)) << 5) + off;
    const float* pd = cellbase + ((((yi1 >> 3) << 5) + (xi1 >> 3)) << 5) + off;

    float r[8];
#pragma unroll
    for (int k = 0; k < 2; ++k) {
        float4 va = *(const float4*)(pa + 4 * k);
        float4 vb = *(const float4*)(pb + 4 * k);
        float4 vc = *(const float4*)(pc + 4 * k);
        float4 vd = *(const float4*)(pd + 4 * k);
        r[4 * k]     = fmaf(wa, va.x, fmaf(wb, vb.x, fmaf(wc, vc.x, wd * vd.x)));
        r[4 * k + 1] = fmaf(wa, va.y, fmaf(wb, vb.y, fmaf(wc, vc.y, wd * vd.y)));
        r[4 * k + 2] = fmaf(wa, va.z, fmaf(wb, vb.z, fmaf(wc, vc.z, wd * vd.z)));
        r[4 * k + 3] = fmaf(wa, va.w, fmaf(wb, vb.w, fmaf(wc, vc.w, wd * vd.w)));
    }
    if (q == 0) {
        const float* xb = x + b * 65536;
        float Ia = xb[yi0 * 256 + xi0];
        float Ib = xb[yi1 * 256 + xi0];
        float Ic = xb[yi0 * 256 + xi1];
        float Id = xb[yi1 * 256 + xi1];
        r[0] = fmaf(wa, Ia, fmaf(wb, Ib, fmaf(wc, Ic, wd * Id)));
    }
#pragma unroll
    for (int i = 0; i < 8; ++i) r[i] = r[i] >= 0.0f ? r[i] : NEG_SLOPE * r[i];

    float* ob = out + pix * 32 + off;
    vfloat4 v0 = {r[0], r[1], r[2], r[3]};
    vfloat4 v1 = {r[4], r[5], r[6], r[7]};
    __builtin_nontemporal_store(v0, (vfloat4*)ob);
    __builtin_nontemporal_store(v1, (vfloat4*)(ob + 4));
}

extern "C" void kernel_launch(void* const* d_in, const int* in_sizes, int n_in,
                              void* d_out, int out_size, void* d_ws, size_t ws_size,
                              hipStream_t stream) {
    const float* x     = (const float*)d_in[0];
    const float* c1k   = (const float*)d_in[1];
    const float* c1b   = (const float*)d_in[2];
    const float* c2k   = (const float*)d_in[3];
    const float* c2b   = (const float*)d_in[4];
    const float* c3k   = (const float*)d_in[5];
    const float* c3b   = (const float*)d_in[6];
    const float* gamma = (const float*)d_in[7];
    const float* beta  = (const float*)d_in[8];
    const float* mean  = (const float*)d_in[9];
    const float* var   = (const float*)d_in[10];
    const float* d1k   = (const float*)d_in[11];
    const float* d1b   = (const float*)d_in[12];
    const float* d2k   = (const float*)d_in[13];
    const float* d2b   = (const float*)d_in[14];
    const float* d3k   = (const float*)d_in[15];
    const float* d3b   = (const float*)d_in[16];
    float* out = (float*)d_out;
    float* ws  = (float*)d_ws;

    float* Ap      = ws;                           // 16*130*130*8 = 2163200
    float* Bp      = ws + 2163200;                 // 16*66*66*16 = 1115136
    float* xip     = ws;                           // 524288 (reuse Ap)
    float* fprime  = ws + 524288;                  // 507904 (reuse Ap)
    float* partial = ws + 3278336;                 // 496*64*16 = 507904
    float* theta   = ws + 3786240;                 // 96

    st_conv1<<<1024, 256, 0, stream>>>(x, c1k, c1b, Ap, Bp);
    st_conv2<<<1024, 256, 0, stream>>>(Ap, c2k, c2b, Bp);
    st_conv3p<<<dim3(256, 2), 256, 0, stream>>>(Bp, c3k, c3b, gamma, beta,
                                                mean, var, xip, fprime);
    st_d1<<<496, 256, 0, stream>>>(fprime, d1k, partial);
    st_head<<<16, 256, 0, stream>>>(partial, d1b, d2k, d2b, d3k, d3b, theta);
    st_sample<<<16384, 256, 0, stream>>>(x, xip, theta, out);
}